// Round 17
// baseline (527.930 us; speedup 1.0000x reference)
//
#include <hip/hip_runtime.h>
#include <stdint.h>

#define HW    480
#define KS    24
#define CH    3
#define HO    457            // 480-24+1
#define NPOS  (HO*HO)        // 208849
#define NP    400
#define PS    (CH*KS*KS)     // 1728
#define SIG   1e-6f
#define NSQ   54             // exact K32 steps: 1728/32
#define NMT   13             // 32-patch MFMA tiles (416 padded patches)
#define NIY   115            // ceil(457/4) row-quads
#define NGRP  (NIY*8*4)      // 3680: (iy,jx,row-in-quad) coarse groups (64 j each)
#define MAXF  16384
#define RGRID 4096           // rescore grid (stride loop over flags)
#define DELTA 4e-3f          // ~11 sigma of int8 coarse corr error (3.5e-4)
#define QS    28.0f          // int8 scale (clip at 127/28 = 4.54 sigma)
#define IS2   (1.0f/(QS*QS))
#define PLS   2592           // plane stride bytes: 27 rows x 96
#define CHS   (4*PLS)        // per-channel block: 4 shift-planes = 10368 B
#define LDSZ  (3*CHS)        // 31104 B total

typedef __attribute__((ext_vector_type(4)))  int  int4v;
typedef __attribute__((ext_vector_type(16))) int  int16v;
typedef unsigned int uint;
typedef unsigned char uchar;
typedef unsigned long long ull;

static __device__ __forceinline__ char q8(float v) {
    float s = rintf(v * QS);
    s = fminf(127.f, fmaxf(-127.f, s));
    return (char)(int)s;
}
static __device__ __forceinline__ uint mono(float f) {      // order-preserving f32->u32
    uint u = __float_as_uint(f);
    return (u & 0x80000000u) ? ~u : (u | 0x80000000u);
}
static __device__ __forceinline__ float unmono(uint u) {
    uint b = (u & 0x80000000u) ? (u & 0x7fffffffu) : ~u;
    return __uint_as_float(b);
}

// ---------------- fat prep kernel 1: repack + y-quant + colsum ----------------
__global__ void fat1_k(const float* __restrict__ x, const float* __restrict__ yd,
                       float* __restrict__ Wp, char* __restrict__ yq,
                       float* __restrict__ cs, float* __restrict__ cs2) {
    int b = blockIdx.x;
    if (b < 2700) {                       // repack: x_dec patches -> Wp[p][c][kh][kw]
        int t = b * 256 + threadIdx.x;    // 2700*256 == NP*PS exactly
        int p = t / PS, e = t - p * PS;
        int c = e / (KS * KS);
        int r = (e / KS) % KS;
        int w = e % KS;
        int pr = p / 20, pc = p - pr * 20;
        Wp[t] = x[c * HW * HW + (pr * KS + r) * HW + (pc * KS + w)];
    } else if (b < 5400) {                // y_dec -> int8 (scale QS)
        int t = (b - 2700) * 256 + threadIdx.x;
        yq[t] = q8(yd[t]);
    } else {                              // colsum: vertical 24-row sums
        int t = (b - 5400) * 256 + threadIdx.x;
        if (t >= HO * HW) return;
        int i = t / HW, w = t - i * HW;
        float s = 0.f, s2 = 0.f;
        for (int c = 0; c < CH; c++) {
            const float* base = yd + c * HW * HW + i * HW + w;
            for (int dh = 0; dh < KS; dh++) {
                float v = base[dh * HW];
                s += v; s2 += v * v;
            }
        }
        cs[t] = s; cs2[t] = s2;
    }
}

// ---------------- fat prep kernel 2: stats + packAq + window + init ----------------
// Aq layout: byte id = ((mtg*54 + s)*64 + lane)*16 + e;
// A[m][k]: m = lane&31, k = (lane>>5)*16 + e, kk = 32s + k (flat [c][kh][kw]).
__global__ void fat2_k(const float* __restrict__ Wp,
                       const float* __restrict__ cs, const float* __restrict__ cs2,
                       float* __restrict__ meanX, float* __restrict__ denXa,
                       char* __restrict__ Aq,
                       float* __restrict__ sumY, float* __restrict__ denYa,
                       uint* __restrict__ cnt, ull* __restrict__ best) {
    __shared__ float shs[4], shs2[4];
    int b = blockIdx.x;
    if (b < 400) {                        // stats for patch b (+ init best/cnt)
        int p = b;
        if (threadIdx.x == 1) best[p] = 0ull;
        if (b == 0 && threadIdx.x == 2) *cnt = 0u;
        float s = 0.f, s2 = 0.f;
        for (int e = threadIdx.x; e < PS; e += 256) {
            float v = Wp[p * PS + e];
            s += v; s2 += v * v;
        }
        for (int o = 32; o > 0; o >>= 1) { s += __shfl_down(s, o); s2 += __shfl_down(s2, o); }
        int lane = threadIdx.x & 63, wv = threadIdx.x >> 6;
        if (lane == 0) { shs[wv] = s; shs2[wv] = s2; }
        __syncthreads();
        if (threadIdx.x == 0) {
            float S = shs[0] + shs[1] + shs[2] + shs[3];
            float S2 = shs2[0] + shs2[1] + shs2[2] + shs2[3];
            float m = S / (float)PS;
            meanX[p] = m;
            denXa[p] = fabsf(S2 / (float)PS - m * m);
        }
    } else if (b < 3208) {                // packAq: A int8 fragments, exact K
        int id = (b - 400) * 256 + threadIdx.x;   // 2808*256 == NMT*54*1024 exactly
        int e    = id & 15;
        int lane = (id >> 4) & 63;
        int f    = id >> 10;
        int s    = f % NSQ;
        int mtg  = f / NSQ;
        int kk = s * 32 + (lane >> 5) * 16 + e;
        int p  = mtg * 32 + (lane & 31);
        float v = (p < NP) ? Wp[p * PS + kk] : 0.f;
        Aq[id] = q8(v);
    } else {                              // window: horizontal 24-col sums
        int t = (b - 3208) * 256 + threadIdx.x;
        if (t >= NPOS) return;
        int i = t / HO, j = t - i * HO;
        const float* r  = cs  + i * HW + j;
        const float* r2 = cs2 + i * HW + j;
        float s = 0.f, s2 = 0.f;
        for (int d = 0; d < KS; d++) { s += r[d]; s2 += r2[d]; }
        sumY[t] = s;
        float ips = 1.0f / (float)PS;
        denYa[t] = fabsf(s2 * ips - (s * ips) * (s * ips));
    }
}

// ---------------- phase1 staging: 3 channels x 4 even-shift planes ----------------
static __device__ __forceinline__ void stage_all(uchar* __restrict__ S,
                                                 const char* __restrict__ yq,
                                                 int i0, int j0, int tid) {
    for (int it = tid; it < 3 * 27 * 6; it += 256) {
        int ch  = it / 162, rem = it - ch * 162;
        int row = rem / 6,  gb  = rem - row * 6;
        int yr  = i0 + row;
        int gj  = j0 + gb * 16;
        uint d[6];
        if (yr < HW && gj + 24 <= HW) {
            const uchar* src = (const uchar*)yq + ((size_t)(ch * HW + yr)) * HW + gj;
            uint4 a = *(const uint4*)src;           // 16B-aligned (gj%16==0)
            uint2 bb = *(const uint2*)(src + 16);
            d[0] = a.x; d[1] = a.y; d[2] = a.z; d[3] = a.w; d[4] = bb.x; d[5] = bb.y;
        } else {
            uchar tmp[24];
#pragma unroll
            for (int e = 0; e < 24; e++) {
                int col = gj + e;
                tmp[e] = (yr < HW && col < HW)
                       ? ((const uchar*)yq)[((size_t)(ch * HW + yr)) * HW + col] : (uchar)0;
            }
            const uint* tp = (const uint*)tmp;
#pragma unroll
            for (int e = 0; e < 6; e++) d[e] = tp[e];
        }
        int base = ch * CHS + row * 96 + gb * 16;
        uint s0 = (d[0] >> 16) | (d[1] << 16);
        uint s1 = (d[1] >> 16) | (d[2] << 16);
        uint s2 = (d[2] >> 16) | (d[3] << 16);
        uint s3 = (d[3] >> 16) | (d[4] << 16);
        uint s4 = (d[4] >> 16) | (d[5] << 16);
        *(uint4*)&S[base]           = make_uint4(d[0], d[1], d[2], d[3]);  // shift 0
        *(uint4*)&S[base + PLS]     = make_uint4(s0, s1, s2, s3);          // shift 2
        *(uint4*)&S[base + 2*PLS]   = make_uint4(d[1], d[2], d[3], d[4]);  // shift 4
        *(uint4*)&S[base + 3*PLS]   = make_uint4(s1, s2, s3, s4);          // shift 6
    }
}

// ---------------- phase1: coarse int8 correlation, per-group max ----------------
// R16 (resubmitted after broker timeout): SINGLE-PHASE merge — grid(8,115),
// each block stages its yq window ONCE and runs all 13 MT=1 bodies over it.
// Staging passes 3->1; Aq stream (718KB) L2-resident; co-residency hard cap
// 920 blocks = 3.59/CU. If neutral, config space on this axis is exhausted:
// latency-bound plateau at ~2.7x the 77us MFMA floor.
// [Closed: 2-plane+v_perm (R13/R14), z-fastest (R9), MT=2 (R10), dbuf (R5),
// barriers (R5/R6), tree-rotate epilogue (R4).]
// Barrier-free Q-loop, 4 even-shift planes + const-sel v_perm t=1 extract,
// A ping-pong prefetch, s_setprio around MFMA cluster. VGPR 48.
static __device__ __forceinline__ void corr1_body(
        const int mt0, const int jx, const int iy,
        const char* __restrict__ Aq,
        const float* __restrict__ meanX, const float* __restrict__ denXa,
        const float* __restrict__ sumY, const float* __restrict__ denYa,
        uint* __restrict__ table, const uchar* __restrict__ S) {
    const int tid  = threadIdx.x;
    const int lane = tid & 63;
    const int g    = tid >> 6;      // wave = row within quad
    const int n    = lane & 31;
    const int kha  = lane >> 5;
    const int j0   = 64 * jx;
    const int i0   = 4 * iy;
    const int i    = i0 + g;

    // per-(u,kha) in-plane byte offsets (row stride 96 B); all == 0 mod 8
    const int olo[3] = { kha ? 16  : 0,   kha ? 192 : 104, kha ? 296 : 208 };
    const int ohi[3] = { kha ? 96  : 8,   kha ? 200 : 112, kha ? 304 : 288 };

    // lane-fixed base: plane (n&3) (= byte shift (2n)&6), 8-aligned col, row g
    const uchar* Sp = S + (n & 3) * PLS + ((2 * n) & ~7) + g * 96;

    const char* Ab = Aq + ((size_t)mt0 * NSQ << 10) + lane * 16;

    int16v acc[2];   // [t]
#pragma unroll
    for (int t = 0; t < 2; t++) acc[t] = (int16v)0;

    // A ping-pong fragments; prologue loads chunk-set Q=0
    int4v av[2][3];
#pragma unroll
    for (int u = 0; u < 3; u++)
        av[0][u] = *(const int4v*)(Ab + (u << 10));

#pragma unroll
    for (int Q = 0; Q < 18; Q++) {
        const int cur = Q & 1;
        if (Q < 17) {                     // prefetch next Q's A chunks
#pragma unroll
            for (int u = 0; u < 3; u++)
                av[cur ^ 1][u] = *(const int4v*)(Ab + (((Q + 1) * 3 + u) << 10));
        }
        const int IQ = (Q / 6) * CHS + (Q % 6) * 384;   // compile-time immediate
        __builtin_amdgcn_s_setprio(1);
#pragma unroll
        for (int u = 0; u < 3; u++) {
            // two 16B windows (lo/hi pieces), aligned b64 pairs
            uint2 wl0 = *(const uint2*)(Sp + IQ + olo[u]);
            uint2 wl1 = *(const uint2*)(Sp + IQ + olo[u] + 8);
            uint2 wh0 = *(const uint2*)(Sp + IQ + ohi[u]);
            uint2 wh1 = *(const uint2*)(Sp + IQ + ohi[u] + 8);
            int4v bv0, bv1;
            bv0.x = (int)wl0.x; bv0.y = (int)wl0.y;
            bv0.z = (int)wh0.x; bv0.w = (int)wh0.y;
            bv1.x = (int)__builtin_amdgcn_perm(wl0.y, wl0.x, 0x04030201u);
            bv1.y = (int)__builtin_amdgcn_perm(wl1.x, wl0.y, 0x04030201u);
            bv1.z = (int)__builtin_amdgcn_perm(wh0.y, wh0.x, 0x04030201u);
            bv1.w = (int)__builtin_amdgcn_perm(wh1.x, wh0.y, 0x04030201u);
            acc[0] = __builtin_amdgcn_mfma_i32_32x32x32_i8(av[cur][u], bv0, acc[0], 0, 0, 0);
            acc[1] = __builtin_amdgcn_mfma_i32_32x32x32_i8(av[cur][u], bv1, acc[1], 0, 0, 0);
        }
        __builtin_amdgcn_s_setprio(0);
    }

    // ---- epilogue: coarse corr, per-(patch, group) max (R2-identical) ----
    const int grp = (iy * 8 + jx) * 4 + g;
    const float c2 = 2.0f / (float)PS;
    const bool iok = i < HO;
    float sYv[2], rDv[2];
#pragma unroll
    for (int t = 0; t < 2; t++) {
        int j = j0 + 2 * n + t;
        bool ok = iok && (j < HO);
        sYv[t] = ok ? sumY[i * HO + j] : 0.f;
        rDv[t] = ok ? denYa[i * HO + j] : 0.f;
    }
    const bool jv0 = iok && (j0 + 2 * n + 0 < HO);
    const bool jv1 = iok && (j0 + 2 * n + 1 < HO);
    const int pbase = mt0 * 32;
#pragma unroll
    for (int r = 0; r < 16; r++) {
        int p = pbase + (r & 3) + 8 * (r >> 2) + 4 * kha;
        bool pok = p < NP;
        float mX = pok ? meanX[p] : 0.f;
        float dX = pok ? denXa[p] : 0.f;
        float num[2], den[2];
#pragma unroll
        for (int t = 0; t < 2; t++) {
            bool ok = t ? jv1 : jv0;
            if (ok) {
                float xy = (float)acc[t][r] * IS2;
                num[t] = fmaf(-mX, sYv[t], xy) * c2 + SIG;
                den[t] = dX + rDv[t] + SIG;
            } else {
                num[t] = -3.0e38f;
                den[t] = 1.0f;
            }
        }
        // pick larger ratio via cross-mul (dens > 0), single rcp
        bool pick1 = num[1] * den[0] > num[0] * den[1];
        float nn = pick1 ? num[1] : num[0];
        float dd = pick1 ? den[1] : den[0];
        float bu = nn * __builtin_amdgcn_rcpf(dd);
#pragma unroll
        for (int o = 1; o < 32; o <<= 1)
            bu = fmaxf(bu, __shfl_xor(bu, o));
        if (n == 0 && pok) table[p * NGRP + grp] = mono(bu);
    }
}

__launch_bounds__(256, 5)
__global__ void corr1_k(const char* __restrict__ yq, const char* __restrict__ Aq,
                        const float* __restrict__ meanX, const float* __restrict__ denXa,
                        const float* __restrict__ sumY, const float* __restrict__ denYa,
                        uint* __restrict__ table) {
    __shared__ __align__(16) uchar S[LDSZ];   // 31104 B (3 ch x 4 shift-planes)
    const int jx = blockIdx.x;
    const int iy = blockIdx.y;
    stage_all(S, yq, 4 * iy, 64 * jx, threadIdx.x);
    __syncthreads();     // the ONLY barrier; S is read-only afterwards
#pragma unroll 1
    for (int mt0 = 0; mt0 < NMT; mt0++)
        corr1_body(mt0, jx, iy, Aq, meanX, denXa, sumY, denYa, table, S);
}

// ---------------- phase2a: per-patch threshold + flagged-group emission ----------------
__global__ void flag_k(const uint* __restrict__ table,
                       uint* __restrict__ flags, uint* __restrict__ cnt) {
    __shared__ uint sm[4];
    __shared__ float sthr;
    int p = blockIdx.x;
    uint m = 0;
    for (int g = threadIdx.x; g < NGRP; g += 256) {
        uint v = table[p * NGRP + g];
        m = v > m ? v : m;
    }
    for (int o = 32; o > 0; o >>= 1) { uint ot = __shfl_down(m, o); m = ot > m ? ot : m; }
    int lane = threadIdx.x & 63, wv = threadIdx.x >> 6;
    if (lane == 0) sm[wv] = m;
    __syncthreads();
    if (threadIdx.x == 0) {
        uint mm = max(max(sm[0], sm[1]), max(sm[2], sm[3]));
        sthr = unmono(mm) - DELTA;
    }
    __syncthreads();
    float thr = sthr;
    for (int g = threadIdx.x; g < NGRP; g += 256) {
        if (unmono(table[p * NGRP + g]) >= thr) {
            uint idx = atomicAdd(cnt, 1u);
            if (idx < MAXF) flags[idx] = (uint)(p * NGRP + g);
        }
    }
}

// ---------------- phase2b: exact fp32 rescoring of flagged groups ----------------
// Grid RGRID with stride loop (nflag typically << MAXF).
__launch_bounds__(64)
__global__ void rescore_k(const float* __restrict__ Wp, const float* __restrict__ y_dec,
                          const float* __restrict__ meanX, const float* __restrict__ denXa,
                          const float* __restrict__ sumY, const float* __restrict__ denYa,
                          const uint* __restrict__ flags, const uint* __restrict__ cnt,
                          ull* __restrict__ best) {
    uint nflag = *cnt; if (nflag > MAXF) nflag = MAXF;
    for (uint fb = blockIdx.x; fb < nflag; fb += RGRID) {
        uint f = flags[fb];
        int p = f / NGRP, grp = f - p * NGRP;
        int g = grp & 3, bj = grp >> 2;
        int jx = bj & 7, iy = bj >> 3;
        int i = 4 * iy + g;
        int j = 64 * jx + threadIdx.x;
        ull pk = 0;
        if (i < HO && j < HO) {
            float dot = 0.f;
            const float* wr = Wp + p * PS;
            for (int c = 0; c < CH; c++)
                for (int kh = 0; kh < KS; kh++) {
                    const float* yr = y_dec + ((c * HW) + i + kh) * HW + j;
                    const float* wk = wr + (c * KS + kh) * KS;
#pragma unroll
                    for (int kw = 0; kw < KS; kw++) dot += wk[kw] * yr[kw];
                }
            float corr = (2.0f * (dot - meanX[p] * sumY[i * HO + j]) * (1.0f / (float)PS) + SIG)
                       / (denXa[p] + denYa[i * HO + j] + SIG);
            uint idx = (uint)(i * HO + j);
            pk = ((ull)mono(corr) << 32) | (uint)(~idx);   // first-max tie-break via ~idx
        }
        for (int o = 32; o > 0; o >>= 1) { ull ot = __shfl_down(pk, o); pk = ot > pk ? ot : pk; }
        if (threadIdx.x == 0) atomicMax(&best[p], pk);
    }
}

// ---------------- gather ----------------
__global__ void gather_k(const float* __restrict__ y,
                         const ull* __restrict__ best,
                         float* __restrict__ out) {
    int p = blockIdx.x;
    uint idx = ~((uint)(best[p] & 0xFFFFFFFFull));
    int r = idx / HO, cc = idx - r * HO;
    int pr = p / 20, pc = p - pr * 20;
    for (int e = threadIdx.x; e < PS; e += 256) {
        int c = e / (KS * KS);
        int kh = (e / KS) % KS;
        int kw = e % KS;
        out[c * HW * HW + (pr * KS + kh) * HW + (pc * KS + kw)] =
            y[c * HW * HW + (r + kh) * HW + (cc + kw)];
    }
}

// ---------------- launch ----------------
extern "C" void kernel_launch(void* const* d_in, const int* in_sizes, int n_in,
                              void* d_out, int out_size, void* d_ws, size_t ws_size,
                              hipStream_t stream) {
    const float* x_dec = (const float*)d_in[0];
    const float* y_dec = (const float*)d_in[1];
    const float* y     = (const float*)d_in[2];
    float* out = (float*)d_out;

    char* ws = (char*)d_ws;
    size_t off = 0;
    auto carve = [&](size_t bytes) -> void* {
        void* p = ws + off;
        off += (bytes + 255) & ~(size_t)255;
        return p;
    };
    float*  Wp    = (float*)carve((size_t)NP * PS * 4);           // 2.77 MB
    char*   yq    = (char*)carve((size_t)CH * HW * HW);           // 0.69 MB
    char*   Aq    = (char*)carve((size_t)NMT * NSQ * 1024);       // 0.72 MB
    float*  cs    = (float*)carve((size_t)HO * HW * 4);
    float*  cs2   = (float*)carve((size_t)HO * HW * 4);
    float*  sumY  = (float*)carve((size_t)NPOS * 4);
    float*  denYa = (float*)carve((size_t)NPOS * 4);
    float*  meanX = (float*)carve((size_t)NP * 4);
    float*  denXa = (float*)carve((size_t)NP * 4);
    uint*   table = (uint*)carve((size_t)NP * NGRP * 4);          // 5.89 MB
    uint*   flags = (uint*)carve((size_t)MAXF * 4);
    uint*   cnt   = (uint*)carve(256);
    ull*    best  = (ull*)carve((size_t)NP * 8);

    fat1_k<<<6257, 256, 0, stream>>>(x_dec, y_dec, Wp, yq, cs, cs2);
    fat2_k<<<4024, 256, 0, stream>>>(Wp, cs, cs2, meanX, denXa, Aq, sumY, denYa, cnt, best);

    dim3 grid(8, NIY);
    corr1_k<<<grid, 256, 0, stream>>>(yq, Aq, meanX, denXa, sumY, denYa, table);

    flag_k<<<NP, 256, 0, stream>>>(table, flags, cnt);
    rescore_k<<<RGRID, 64, 0, stream>>>(Wp, y_dec, meanX, denXa, sumY, denYa, flags, cnt, best);

    gather_k<<<NP, 256, 0, stream>>>(y, best, out);
}

// Round 18
// 335.170 us; speedup vs baseline: 1.5751x; 1.5751x over previous
//
#include <hip/hip_runtime.h>
#include <stdint.h>

#define HW    480
#define KS    24
#define CH    3
#define HO    457            // 480-24+1
#define NPOS  (HO*HO)        // 208849
#define NP    400
#define PS    (CH*KS*KS)     // 1728
#define SIG   1e-6f
#define NSQ   54             // exact K32 steps: 1728/32
#define NMT   13             // 32-patch MFMA tiles (416 padded patches)
#define NIY   115            // ceil(457/4) row-quads
#define NGRP  (NIY*8*4)      // 3680: (iy,jx,row-in-quad) coarse groups (64 j each)
#define MAXF  16384
#define RGRID 4096           // rescore grid (stride loop over flags)
#define DELTA 4e-3f          // ~11 sigma of int8 coarse corr error (3.5e-4)
#define QS    28.0f          // int8 scale (clip at 127/28 = 4.54 sigma)
#define IS2   (1.0f/(QS*QS))
#define PLS   2592           // plane stride bytes: 27 rows x 96
#define CHS   (4*PLS)        // per-channel block: 4 shift-planes = 10368 B
#define LDSZ  (3*CHS)        // 31104 B total

typedef __attribute__((ext_vector_type(4)))  int  int4v;
typedef __attribute__((ext_vector_type(16))) int  int16v;
typedef unsigned int uint;
typedef unsigned char uchar;
typedef unsigned long long ull;

static __device__ __forceinline__ char q8(float v) {
    float s = rintf(v * QS);
    s = fminf(127.f, fmaxf(-127.f, s));
    return (char)(int)s;
}
static __device__ __forceinline__ uint mono(float f) {      // order-preserving f32->u32
    uint u = __float_as_uint(f);
    return (u & 0x80000000u) ? ~u : (u | 0x80000000u);
}
static __device__ __forceinline__ float unmono(uint u) {
    uint b = (u & 0x80000000u) ? (u & 0x7fffffffu) : ~u;
    return __uint_as_float(b);
}

// ---------------- fat prep kernel 1: repack + y-quant + colsum ----------------
__global__ void fat1_k(const float* __restrict__ x, const float* __restrict__ yd,
                       float* __restrict__ Wp, char* __restrict__ yq,
                       float* __restrict__ cs, float* __restrict__ cs2) {
    int b = blockIdx.x;
    if (b < 2700) {                       // repack: x_dec patches -> Wp[p][c][kh][kw]
        int t = b * 256 + threadIdx.x;    // 2700*256 == NP*PS exactly
        int p = t / PS, e = t - p * PS;
        int c = e / (KS * KS);
        int r = (e / KS) % KS;
        int w = e % KS;
        int pr = p / 20, pc = p - pr * 20;
        Wp[t] = x[c * HW * HW + (pr * KS + r) * HW + (pc * KS + w)];
    } else if (b < 5400) {                // y_dec -> int8 (scale QS)
        int t = (b - 2700) * 256 + threadIdx.x;
        yq[t] = q8(yd[t]);
    } else {                              // colsum: vertical 24-row sums
        int t = (b - 5400) * 256 + threadIdx.x;
        if (t >= HO * HW) return;
        int i = t / HW, w = t - i * HW;
        float s = 0.f, s2 = 0.f;
        for (int c = 0; c < CH; c++) {
            const float* base = yd + c * HW * HW + i * HW + w;
            for (int dh = 0; dh < KS; dh++) {
                float v = base[dh * HW];
                s += v; s2 += v * v;
            }
        }
        cs[t] = s; cs2[t] = s2;
    }
}

// ---------------- fat prep kernel 2: stats + packAq + window + init ----------------
// Aq layout: byte id = ((mtg*54 + s)*64 + lane)*16 + e;
// A[m][k]: m = lane&31, k = (lane>>5)*16 + e, kk = 32s + k (flat [c][kh][kw]).
__global__ void fat2_k(const float* __restrict__ Wp,
                       const float* __restrict__ cs, const float* __restrict__ cs2,
                       float* __restrict__ meanX, float* __restrict__ denXa,
                       char* __restrict__ Aq,
                       float* __restrict__ sumY, float* __restrict__ denYa,
                       uint* __restrict__ cnt, ull* __restrict__ best) {
    __shared__ float shs[4], shs2[4];
    int b = blockIdx.x;
    if (b < 400) {                        // stats for patch b (+ init best/cnt)
        int p = b;
        if (threadIdx.x == 1) best[p] = 0ull;
        if (b == 0 && threadIdx.x == 2) *cnt = 0u;
        float s = 0.f, s2 = 0.f;
        for (int e = threadIdx.x; e < PS; e += 256) {
            float v = Wp[p * PS + e];
            s += v; s2 += v * v;
        }
        for (int o = 32; o > 0; o >>= 1) { s += __shfl_down(s, o); s2 += __shfl_down(s2, o); }
        int lane = threadIdx.x & 63, wv = threadIdx.x >> 6;
        if (lane == 0) { shs[wv] = s; shs2[wv] = s2; }
        __syncthreads();
        if (threadIdx.x == 0) {
            float S = shs[0] + shs[1] + shs[2] + shs[3];
            float S2 = shs2[0] + shs2[1] + shs2[2] + shs2[3];
            float m = S / (float)PS;
            meanX[p] = m;
            denXa[p] = fabsf(S2 / (float)PS - m * m);
        }
    } else if (b < 3208) {                // packAq: A int8 fragments, exact K
        int id = (b - 400) * 256 + threadIdx.x;   // 2808*256 == NMT*54*1024 exactly
        int e    = id & 15;
        int lane = (id >> 4) & 63;
        int f    = id >> 10;
        int s    = f % NSQ;
        int mtg  = f / NSQ;
        int kk = s * 32 + (lane >> 5) * 16 + e;
        int p  = mtg * 32 + (lane & 31);
        float v = (p < NP) ? Wp[p * PS + kk] : 0.f;
        Aq[id] = q8(v);
    } else {                              // window: horizontal 24-col sums
        int t = (b - 3208) * 256 + threadIdx.x;
        if (t >= NPOS) return;
        int i = t / HO, j = t - i * HO;
        const float* r  = cs  + i * HW + j;
        const float* r2 = cs2 + i * HW + j;
        float s = 0.f, s2 = 0.f;
        for (int d = 0; d < KS; d++) { s += r[d]; s2 += r2[d]; }
        sumY[t] = s;
        float ips = 1.0f / (float)PS;
        denYa[t] = fabsf(s2 * ips - (s * ips) * (s * ips));
    }
}

// ---------------- phase1 staging: 3 channels x 4 even-shift planes ----------------
static __device__ __forceinline__ void stage_all(uchar* __restrict__ S,
                                                 const char* __restrict__ yq,
                                                 int i0, int j0, int tid) {
    for (int it = tid; it < 3 * 27 * 6; it += 256) {
        int ch  = it / 162, rem = it - ch * 162;
        int row = rem / 6,  gb  = rem - row * 6;
        int yr  = i0 + row;
        int gj  = j0 + gb * 16;
        uint d[6];
        if (yr < HW && gj + 24 <= HW) {
            const uchar* src = (const uchar*)yq + ((size_t)(ch * HW + yr)) * HW + gj;
            uint4 a = *(const uint4*)src;           // 16B-aligned (gj%16==0)
            uint2 bb = *(const uint2*)(src + 16);
            d[0] = a.x; d[1] = a.y; d[2] = a.z; d[3] = a.w; d[4] = bb.x; d[5] = bb.y;
        } else {
            uchar tmp[24];
#pragma unroll
            for (int e = 0; e < 24; e++) {
                int col = gj + e;
                tmp[e] = (yr < HW && col < HW)
                       ? ((const uchar*)yq)[((size_t)(ch * HW + yr)) * HW + col] : (uchar)0;
            }
            const uint* tp = (const uint*)tmp;
#pragma unroll
            for (int e = 0; e < 6; e++) d[e] = tp[e];
        }
        int base = ch * CHS + row * 96 + gb * 16;
        uint s0 = (d[0] >> 16) | (d[1] << 16);
        uint s1 = (d[1] >> 16) | (d[2] << 16);
        uint s2 = (d[2] >> 16) | (d[3] << 16);
        uint s3 = (d[3] >> 16) | (d[4] << 16);
        uint s4 = (d[4] >> 16) | (d[5] << 16);
        *(uint4*)&S[base]           = make_uint4(d[0], d[1], d[2], d[3]);  // shift 0
        *(uint4*)&S[base + PLS]     = make_uint4(s0, s1, s2, s3);          // shift 2
        *(uint4*)&S[base + 2*PLS]   = make_uint4(d[1], d[2], d[3], d[4]);  // shift 4
        *(uint4*)&S[base + 3*PLS]   = make_uint4(s1, s2, s3, s4);          // shift 6
    }
}

// ---------------- phase1: coarse int8 correlation, per-group max ----------------
// FINAL (R12 config, session best: corr1 217.6us, total 338.1us).
// grid(8=jx, 115=iy, 4=z), z SLOWEST: 4 sequential phases, each keeping one
// 221KB Aq slice L2-resident on every XCD (FETCH floor ~5.8MB). R17 proved
// this phase partitioning is load-bearing: single-phase merge -> L2 thrash
// (FETCH 894MB, 2x dur) from tile drift + scattered table write-allocate.
// MT=1 bodies x4 per block (R11: TLP lever, VGPR 48, 47% occupancy).
// Barrier-free Q-loop over staged read-only LDS (R6), 4 even-shift planes +
// const-sel v_perm t=1 extract, A ping-pong prefetch one Q ahead (R2),
// s_setprio around MFMA cluster (R7). Invariant across 11 measured rounds:
// MfmaUtil x dur == ~80us == the mfma_i32_32x32x32_i8 pipe floor.
// [Closed axes: barriers/dbuf (R4-R6), staging volume (R6), z-fastest (R9),
// MT=2/4 (R1,R10), 5-6 blk/CU (R12-R14: grid-capped at 920 blk/phase),
// 2-plane v_perm (R13/R14: spill/VALU), phase count 1/3/6 (R15-R17).]
static __device__ __forceinline__ void corr1_body(
        const int mt0, const int jx, const int iy,
        const char* __restrict__ Aq,
        const float* __restrict__ meanX, const float* __restrict__ denXa,
        const float* __restrict__ sumY, const float* __restrict__ denYa,
        uint* __restrict__ table, const uchar* __restrict__ S) {
    const int tid  = threadIdx.x;
    const int lane = tid & 63;
    const int g    = tid >> 6;      // wave = row within quad
    const int n    = lane & 31;
    const int kha  = lane >> 5;
    const int j0   = 64 * jx;
    const int i0   = 4 * iy;
    const int i    = i0 + g;

    // per-(u,kha) in-plane byte offsets (row stride 96 B); all == 0 mod 8
    const int olo[3] = { kha ? 16  : 0,   kha ? 192 : 104, kha ? 296 : 208 };
    const int ohi[3] = { kha ? 96  : 8,   kha ? 200 : 112, kha ? 304 : 288 };

    // lane-fixed base: plane (n&3) (= byte shift (2n)&6), 8-aligned col, row g
    const uchar* Sp = S + (n & 3) * PLS + ((2 * n) & ~7) + g * 96;

    const char* Ab = Aq + ((size_t)mt0 * NSQ << 10) + lane * 16;

    int16v acc[2];   // [t]
#pragma unroll
    for (int t = 0; t < 2; t++) acc[t] = (int16v)0;

    // A ping-pong fragments; prologue loads chunk-set Q=0
    int4v av[2][3];
#pragma unroll
    for (int u = 0; u < 3; u++)
        av[0][u] = *(const int4v*)(Ab + (u << 10));

#pragma unroll
    for (int Q = 0; Q < 18; Q++) {
        const int cur = Q & 1;
        if (Q < 17) {                     // prefetch next Q's A chunks
#pragma unroll
            for (int u = 0; u < 3; u++)
                av[cur ^ 1][u] = *(const int4v*)(Ab + (((Q + 1) * 3 + u) << 10));
        }
        const int IQ = (Q / 6) * CHS + (Q % 6) * 384;   // compile-time immediate
        __builtin_amdgcn_s_setprio(1);
#pragma unroll
        for (int u = 0; u < 3; u++) {
            // two 16B windows (lo/hi pieces), aligned b64 pairs
            uint2 wl0 = *(const uint2*)(Sp + IQ + olo[u]);
            uint2 wl1 = *(const uint2*)(Sp + IQ + olo[u] + 8);
            uint2 wh0 = *(const uint2*)(Sp + IQ + ohi[u]);
            uint2 wh1 = *(const uint2*)(Sp + IQ + ohi[u] + 8);
            int4v bv0, bv1;
            bv0.x = (int)wl0.x; bv0.y = (int)wl0.y;
            bv0.z = (int)wh0.x; bv0.w = (int)wh0.y;
            bv1.x = (int)__builtin_amdgcn_perm(wl0.y, wl0.x, 0x04030201u);
            bv1.y = (int)__builtin_amdgcn_perm(wl1.x, wl0.y, 0x04030201u);
            bv1.z = (int)__builtin_amdgcn_perm(wh0.y, wh0.x, 0x04030201u);
            bv1.w = (int)__builtin_amdgcn_perm(wh1.x, wh0.y, 0x04030201u);
            acc[0] = __builtin_amdgcn_mfma_i32_32x32x32_i8(av[cur][u], bv0, acc[0], 0, 0, 0);
            acc[1] = __builtin_amdgcn_mfma_i32_32x32x32_i8(av[cur][u], bv1, acc[1], 0, 0, 0);
        }
        __builtin_amdgcn_s_setprio(0);
    }

    // ---- epilogue: coarse corr, per-(patch, group) max (R2-identical) ----
    const int grp = (iy * 8 + jx) * 4 + g;
    const float c2 = 2.0f / (float)PS;
    const bool iok = i < HO;
    float sYv[2], rDv[2];
#pragma unroll
    for (int t = 0; t < 2; t++) {
        int j = j0 + 2 * n + t;
        bool ok = iok && (j < HO);
        sYv[t] = ok ? sumY[i * HO + j] : 0.f;
        rDv[t] = ok ? denYa[i * HO + j] : 0.f;
    }
    const bool jv0 = iok && (j0 + 2 * n + 0 < HO);
    const bool jv1 = iok && (j0 + 2 * n + 1 < HO);
    const int pbase = mt0 * 32;
#pragma unroll
    for (int r = 0; r < 16; r++) {
        int p = pbase + (r & 3) + 8 * (r >> 2) + 4 * kha;
        bool pok = p < NP;
        float mX = pok ? meanX[p] : 0.f;
        float dX = pok ? denXa[p] : 0.f;
        float num[2], den[2];
#pragma unroll
        for (int t = 0; t < 2; t++) {
            bool ok = t ? jv1 : jv0;
            if (ok) {
                float xy = (float)acc[t][r] * IS2;
                num[t] = fmaf(-mX, sYv[t], xy) * c2 + SIG;
                den[t] = dX + rDv[t] + SIG;
            } else {
                num[t] = -3.0e38f;
                den[t] = 1.0f;
            }
        }
        // pick larger ratio via cross-mul (dens > 0), single rcp
        bool pick1 = num[1] * den[0] > num[0] * den[1];
        float nn = pick1 ? num[1] : num[0];
        float dd = pick1 ? den[1] : den[0];
        float bu = nn * __builtin_amdgcn_rcpf(dd);
#pragma unroll
        for (int o = 1; o < 32; o <<= 1)
            bu = fmaxf(bu, __shfl_xor(bu, o));
        if (n == 0 && pok) table[p * NGRP + grp] = mono(bu);
    }
}

__launch_bounds__(256, 5)
__global__ void corr1_k(const char* __restrict__ yq, const char* __restrict__ Aq,
                        const float* __restrict__ meanX, const float* __restrict__ denXa,
                        const float* __restrict__ sumY, const float* __restrict__ denYa,
                        uint* __restrict__ table) {
    __shared__ __align__(16) uchar S[LDSZ];   // 31104 B (3 ch x 4 shift-planes)
    const int z  = blockIdx.z;                // z SLOWEST: 4 sequential phases
    const int jx = blockIdx.x;
    const int iy = blockIdx.y;
    stage_all(S, yq, 4 * iy, 64 * jx, threadIdx.x);
    __syncthreads();     // the ONLY barrier; S is read-only afterwards
    if (z == 3) {
        corr1_body(12, jx, iy, Aq, meanX, denXa, sumY, denYa, table, S);
    } else {
        corr1_body(4 * z,     jx, iy, Aq, meanX, denXa, sumY, denYa, table, S);
        corr1_body(4 * z + 1, jx, iy, Aq, meanX, denXa, sumY, denYa, table, S);
        corr1_body(4 * z + 2, jx, iy, Aq, meanX, denXa, sumY, denYa, table, S);
        corr1_body(4 * z + 3, jx, iy, Aq, meanX, denXa, sumY, denYa, table, S);
    }
}

// ---------------- phase2a: per-patch threshold + flagged-group emission ----------------
__global__ void flag_k(const uint* __restrict__ table,
                       uint* __restrict__ flags, uint* __restrict__ cnt) {
    __shared__ uint sm[4];
    __shared__ float sthr;
    int p = blockIdx.x;
    uint m = 0;
    for (int g = threadIdx.x; g < NGRP; g += 256) {
        uint v = table[p * NGRP + g];
        m = v > m ? v : m;
    }
    for (int o = 32; o > 0; o >>= 1) { uint ot = __shfl_down(m, o); m = ot > m ? ot : m; }
    int lane = threadIdx.x & 63, wv = threadIdx.x >> 6;
    if (lane == 0) sm[wv] = m;
    __syncthreads();
    if (threadIdx.x == 0) {
        uint mm = max(max(sm[0], sm[1]), max(sm[2], sm[3]));
        sthr = unmono(mm) - DELTA;
    }
    __syncthreads();
    float thr = sthr;
    for (int g = threadIdx.x; g < NGRP; g += 256) {
        if (unmono(table[p * NGRP + g]) >= thr) {
            uint idx = atomicAdd(cnt, 1u);
            if (idx < MAXF) flags[idx] = (uint)(p * NGRP + g);
        }
    }
}

// ---------------- phase2b: exact fp32 rescoring of flagged groups ----------------
// Grid RGRID with stride loop (nflag typically << MAXF).
__launch_bounds__(64)
__global__ void rescore_k(const float* __restrict__ Wp, const float* __restrict__ y_dec,
                          const float* __restrict__ meanX, const float* __restrict__ denXa,
                          const float* __restrict__ sumY, const float* __restrict__ denYa,
                          const uint* __restrict__ flags, const uint* __restrict__ cnt,
                          ull* __restrict__ best) {
    uint nflag = *cnt; if (nflag > MAXF) nflag = MAXF;
    for (uint fb = blockIdx.x; fb < nflag; fb += RGRID) {
        uint f = flags[fb];
        int p = f / NGRP, grp = f - p * NGRP;
        int g = grp & 3, bj = grp >> 2;
        int jx = bj & 7, iy = bj >> 3;
        int i = 4 * iy + g;
        int j = 64 * jx + threadIdx.x;
        ull pk = 0;
        if (i < HO && j < HO) {
            float dot = 0.f;
            const float* wr = Wp + p * PS;
            for (int c = 0; c < CH; c++)
                for (int kh = 0; kh < KS; kh++) {
                    const float* yr = y_dec + ((c * HW) + i + kh) * HW + j;
                    const float* wk = wr + (c * KS + kh) * KS;
#pragma unroll
                    for (int kw = 0; kw < KS; kw++) dot += wk[kw] * yr[kw];
                }
            float corr = (2.0f * (dot - meanX[p] * sumY[i * HO + j]) * (1.0f / (float)PS) + SIG)
                       / (denXa[p] + denYa[i * HO + j] + SIG);
            uint idx = (uint)(i * HO + j);
            pk = ((ull)mono(corr) << 32) | (uint)(~idx);   // first-max tie-break via ~idx
        }
        for (int o = 32; o > 0; o >>= 1) { ull ot = __shfl_down(pk, o); pk = ot > pk ? ot : pk; }
        if (threadIdx.x == 0) atomicMax(&best[p], pk);
    }
}

// ---------------- gather ----------------
__global__ void gather_k(const float* __restrict__ y,
                         const ull* __restrict__ best,
                         float* __restrict__ out) {
    int p = blockIdx.x;
    uint idx = ~((uint)(best[p] & 0xFFFFFFFFull));
    int r = idx / HO, cc = idx - r * HO;
    int pr = p / 20, pc = p - pr * 20;
    for (int e = threadIdx.x; e < PS; e += 256) {
        int c = e / (KS * KS);
        int kh = (e / KS) % KS;
        int kw = e % KS;
        out[c * HW * HW + (pr * KS + kh) * HW + (pc * KS + kw)] =
            y[c * HW * HW + (r + kh) * HW + (cc + kw)];
    }
}

// ---------------- launch ----------------
extern "C" void kernel_launch(void* const* d_in, const int* in_sizes, int n_in,
                              void* d_out, int out_size, void* d_ws, size_t ws_size,
                              hipStream_t stream) {
    const float* x_dec = (const float*)d_in[0];
    const float* y_dec = (const float*)d_in[1];
    const float* y     = (const float*)d_in[2];
    float* out = (float*)d_out;

    char* ws = (char*)d_ws;
    size_t off = 0;
    auto carve = [&](size_t bytes) -> void* {
        void* p = ws + off;
        off += (bytes + 255) & ~(size_t)255;
        return p;
    };
    float*  Wp    = (float*)carve((size_t)NP * PS * 4);           // 2.77 MB
    char*   yq    = (char*)carve((size_t)CH * HW * HW);           // 0.69 MB
    char*   Aq    = (char*)carve((size_t)NMT * NSQ * 1024);       // 0.72 MB
    float*  cs    = (float*)carve((size_t)HO * HW * 4);
    float*  cs2   = (float*)carve((size_t)HO * HW * 4);
    float*  sumY  = (float*)carve((size_t)NPOS * 4);
    float*  denYa = (float*)carve((size_t)NPOS * 4);
    float*  meanX = (float*)carve((size_t)NP * 4);
    float*  denXa = (float*)carve((size_t)NP * 4);
    uint*   table = (uint*)carve((size_t)NP * NGRP * 4);          // 5.89 MB
    uint*   flags = (uint*)carve((size_t)MAXF * 4);
    uint*   cnt   = (uint*)carve(256);
    ull*    best  = (ull*)carve((size_t)NP * 8);

    fat1_k<<<6257, 256, 0, stream>>>(x_dec, y_dec, Wp, yq, cs, cs2);
    fat2_k<<<4024, 256, 0, stream>>>(Wp, cs, cs2, meanX, denXa, Aq, sumY, denYa, cnt, best);

    dim3 grid(8, NIY, 4);
    corr1_k<<<grid, 256, 0, stream>>>(yq, Aq, meanX, denXa, sumY, denYa, table);

    flag_k<<<NP, 256, 0, stream>>>(table, flags, cnt);
    rescore_k<<<RGRID, 64, 0, stream>>>(Wp, y_dec, meanX, denXa, sumY, denYa, flags, cnt, best);

    gather_k<<<NP, 256, 0, stream>>>(y, best, out);
}